// Round 11
// baseline (293.490 us; speedup 1.0000x reference)
//
#include <hip/hip_runtime.h>
#include <stdint.h>

#define B_ 2
#define S_ 2048
#define D_ 1024
#define H_ 16
#define HD_ 64
#define M_TOT (B_*S_)   // 4096

typedef __bf16 bf16;
typedef bf16 bf16x8 __attribute__((ext_vector_type(8)));
typedef float f32x4 __attribute__((ext_vector_type(4)));
typedef float f32x16 __attribute__((ext_vector_type(16)));
typedef unsigned int u32;
typedef unsigned int u32x4v __attribute__((ext_vector_type(4)));

__device__ __forceinline__ void gload_lds16(const void* g, void* l) {
    __builtin_amdgcn_global_load_lds((const __attribute__((address_space(1))) void*)g,
                                     (__attribute__((address_space(3))) void*)l, 16, 0, 0);
}

__device__ __forceinline__ u32 cvtpk_bf16(float lo, float hi) {
    u32 d;
    asm("v_cvt_pk_bf16_f32 %0, %1, %2" : "=v"(d) : "v"(lo), "v"(hi));
    return d;
}

// ---------------- f32 -> bf16 convert ----------------
__global__ __launch_bounds__(256) void cvt_kernel(
    const float* __restrict__ q, const float* __restrict__ k, const float* __restrict__ v,
    const float* __restrict__ wq, const float* __restrict__ wk,
    const float* __restrict__ wv, const float* __restrict__ wo,
    bf16* __restrict__ xq, bf16* __restrict__ xk, bf16* __restrict__ xv,
    bf16* __restrict__ wqb, bf16* __restrict__ wkb, bf16* __restrict__ wvb, bf16* __restrict__ wob)
{
    const float* src; bf16* dst; int n;
    switch (blockIdx.y) {
        case 0: src=q;  dst=xq;  n=M_TOT*D_; break;
        case 1: src=k;  dst=xk;  n=M_TOT*D_; break;
        case 2: src=v;  dst=xv;  n=M_TOT*D_; break;
        case 3: src=wq; dst=wqb; n=D_*D_;    break;
        case 4: src=wk; dst=wkb; n=D_*D_;    break;
        case 5: src=wv; dst=wvb; n=D_*D_;    break;
        default: src=wo; dst=wob; n=D_*D_;   break;
    }
    int i = (blockIdx.x*blockDim.x + threadIdx.x)*8;
    if (i >= n) return;
    const f32x4* s4 = (const f32x4*)(src + i);
    f32x4 a = s4[0], b = s4[1];
    bf16x8 o;
    #pragma unroll
    for (int j = 0; j < 4; ++j) { o[j] = (bf16)a[j]; o[j+4] = (bf16)b[j]; }
    *(bf16x8*)(dst + i) = o;
}

// ---------------- GEMM mainloop: C[128,128] = A[128,K] * W[128,K]^T ----------------
__device__ __forceinline__ void gemm_mainloop(const bf16* __restrict__ A, const bf16* __restrict__ Wt,
                                              int brow, int bcol, bf16* As, bf16* Bs,
                                              f32x4 (&acc)[4][4])
{
    const int tid = threadIdx.x;
    const int l = tid & 63, w = tid >> 6;
    const int wr = w >> 1, wc = w & 1;
    const int lr = l & 15, lq = l >> 4;

    for (int k0 = 0; k0 < D_; k0 += 32) {
        #pragma unroll
        for (int i = 0; i < 2; ++i) {
            int id = i*256 + tid;
            int row = id >> 2, c8 = (id & 3) << 3;
            gload_lds16(A  + (size_t)(brow + row)*D_ + k0 + c8, As + id*8);
            gload_lds16(Wt + (size_t)(bcol + row)*D_ + k0 + c8, Bs + id*8);
        }
        __syncthreads();
        bf16x8 af[4], bf[4];
        #pragma unroll
        for (int m = 0; m < 4; ++m)
            af[m] = *(const bf16x8*)&As[(wr*64 + m*16 + lr)*32 + lq*8];
        #pragma unroll
        for (int n = 0; n < 4; ++n)
            bf[n] = *(const bf16x8*)&Bs[(wc*64 + n*16 + lr)*32 + lq*8];
        #pragma unroll
        for (int m = 0; m < 4; ++m)
            #pragma unroll
            for (int n = 0; n < 4; ++n)
                acc[m][n] = __builtin_amdgcn_mfma_f32_16x16x32_bf16(af[m], bf[n], acc[m][n], 0, 0, 0);
        __syncthreads();
    }
}

// ---------------- QKV projection GEMM (z: 0=Q,1=K,2=V) ----------------
// Epilogue scatters into MFMA-fragment-major layouts (1KB chunks, lane-ordered):
//  Q/K: chunk=(s>>5)*4+(hd>>4), lane=((hd>>3)&1)<<5 | (s&31), j=hd&7
//  V:   chunk=(s>>6)*8+((s>>4)&3)*2+(hd>>5), lane=((s>>3)&1)<<5 | (hd&31), j=s&7
__global__ __launch_bounds__(256) void gemm_qkv(
    const bf16* __restrict__ xq, const bf16* __restrict__ xk, const bf16* __restrict__ xv,
    const bf16* __restrict__ wqb, const bf16* __restrict__ wkb, const bf16* __restrict__ wvb,
    const float* __restrict__ bq, const float* __restrict__ bk, const float* __restrict__ bv,
    bf16* __restrict__ Qf, bf16* __restrict__ Kf, bf16* __restrict__ Vf)
{
    __shared__ __align__(16) bf16 As[128*32];
    __shared__ __align__(16) bf16 Bs[128*32];
    const int z = blockIdx.z;
    const bf16* A  = (z==0) ? xq  : (z==1) ? xk  : xv;
    const bf16* Wt = (z==0) ? wqb : (z==1) ? wkb : wvb;
    const float* bias = (z==0) ? bq : (z==1) ? bk : bv;

    const int brow = (blockIdx.x & 31)*128;
    const int bcol = (blockIdx.x >> 5)*128;

    f32x4 acc[4][4] = {};
    gemm_mainloop(A, Wt, brow, bcol, As, Bs, acc);

    const int tid = threadIdx.x;
    const int l = tid & 63, w = tid >> 6;
    const int wr = w >> 1, wc = w & 1;
    const int lr = l & 15, lq = l >> 4;

    #pragma unroll
    for (int m = 0; m < 4; ++m)
        #pragma unroll
        for (int n = 0; n < 4; ++n) {
            int col = bcol + wc*64 + n*16 + lr;
            float bv_ = bias[col];
            int h = col >> 6, hd = col & 63;
            #pragma unroll
            for (int r = 0; r < 4; ++r) {
                int row = brow + wr*64 + m*16 + lq*4 + r;
                int b = row >> 11, s = row & 2047;
                float val = acc[m][n][r] + bv_;
                if (z == 0) val *= 0.18033688011112042f;   // 1/sqrt(64) * log2(e) folded into Q
                size_t hbase = ((size_t)b*H_ + h)*S_*HD_;
                if (z < 2) {
                    int chunk = ((s >> 5) << 2) + (hd >> 4);
                    int lane  = (((hd >> 3) & 1) << 5) | (s & 31);
                    bf16* dst = (z==0) ? Qf : Kf;
                    dst[hbase + (size_t)chunk*512 + lane*8 + (hd & 7)] = (bf16)val;
                } else {
                    int chunk = ((s >> 6) << 3) + (((s >> 4) & 3) << 1) + (hd >> 5);
                    int lane  = (((s >> 3) & 1) << 5) | (hd & 31);
                    Vf[hbase + (size_t)chunk*512 + lane*8 + (s & 7)] = (bf16)val;
                }
            }
        }
}

// ---------------- output projection GEMM ----------------
__global__ __launch_bounds__(256) void gemm_out(
    const bf16* __restrict__ Oat, const bf16* __restrict__ wob,
    const float* __restrict__ bo, float* __restrict__ out)
{
    __shared__ __align__(16) bf16 As[128*32];
    __shared__ __align__(16) bf16 Bs[128*32];
    const int brow = (blockIdx.x & 31)*128;
    const int bcol = (blockIdx.x >> 5)*128;

    f32x4 acc[4][4] = {};
    gemm_mainloop(Oat, wob, brow, bcol, As, Bs, acc);

    const int tid = threadIdx.x;
    const int l = tid & 63, w = tid >> 6;
    const int wr = w >> 1, wc = w & 1;
    const int lr = l & 15, lq = l >> 4;

    #pragma unroll
    for (int m = 0; m < 4; ++m)
        #pragma unroll
        for (int n = 0; n < 4; ++n) {
            int col = bcol + wc*64 + n*16 + lr;
            float bv_ = bo[col];
            #pragma unroll
            for (int r = 0; r < 4; ++r) {
                int row = brow + wr*64 + m*16 + lq*4 + r;
                out[(size_t)row*D_ + col] = acc[m][n][r] + bv_;
            }
        }
}

// ---------------- causal flash attention v11: split-K partials (2 waves per q-tile) ----------------
// grid 4096 = 32 bh x 64 qt x 2 halves; 1 wave/block, r7 body (no V-dbuf -> no spills).
// Each wave computes key tiles [ts,te) with its own running (m,l) and UNNORMALIZED O;
// writes bf16 O-partial + f32 (m,l) to scratch. attn_combine merges the 2 partials.
// 2x wave count (4 waves/SIMD at VGPR<=128) to hide the per-iteration latency chain.
#define ATTN_BODY(CUR, NXT, KT) do {                                                        \
    const int kc0_ = (KT)*64;                                                               \
    const bool last_ = ((KT) == nkt - 1);                                                   \
    const int ktn_ = ((KT) + 1 < te) ? (KT) + 1 : (KT);                                     \
    _Pragma("unroll")                                                                       \
    for (int kv2 = 0; kv2 < 2; ++kv2)                                                       \
        _Pragma("unroll")                                                                   \
        for (int dc = 0; dc < 4; ++dc)                                                      \
            NXT[kv2][dc] = *(const bf16x8*)(Kfp + (size_t)((ktn_*2 + kv2)*4 + dc)*512 + l8);\
    bf16x8 va0[4], va1[4];                                                                  \
    _Pragma("unroll")                                                                       \
    for (int c = 0; c < 4; ++c) {                                                           \
        va0[c] = *(const bf16x8*)(Vfp + (size_t)((KT)*8 + c*2 + 0)*512 + l8);               \
        va1[c] = *(const bf16x8*)(Vfp + (size_t)((KT)*8 + c*2 + 1)*512 + l8);               \
    }                                                                                       \
    f32x16 ct0 = {}, ct1 = {};                                                              \
    __builtin_amdgcn_s_setprio(1);                                                          \
    _Pragma("unroll")                                                                       \
    for (int dc = 0; dc < 4; ++dc)                                                          \
        ct0 = __builtin_amdgcn_mfma_f32_32x32x16_bf16(CUR[0][dc], qb[dc], ct0, 0, 0, 0);    \
    _Pragma("unroll")                                                                       \
    for (int dc = 0; dc < 4; ++dc)                                                          \
        ct1 = __builtin_amdgcn_mfma_f32_32x32x16_bf16(CUR[1][dc], qb[dc], ct1, 0, 0, 0);    \
    __builtin_amdgcn_s_setprio(0);                                                          \
    if (last_) {                                                                            \
        _Pragma("unroll")                                                                   \
        for (int reg = 0; reg < 16; ++reg) {                                                \
            const int rr = (reg & 3) + 8*(reg >> 2) + 4*hi;                                 \
            if (kc0_ + rr > qrow)      ct0[reg] = -1e30f;                                   \
            if (kc0_ + 32 + rr > qrow) ct1[reg] = -1e30f;                                   \
        }                                                                                   \
    }                                                                                       \
    float t8[8];                                                                            \
    _Pragma("unroll")                                                                       \
    for (int i = 0; i < 8; ++i)                                                             \
        t8[i] = fmaxf(fmaxf(ct0[i], ct0[i+8]), fmaxf(ct1[i], ct1[i+8]));                    \
    float t4a = fmaxf(t8[0], t8[4]), t4b = fmaxf(t8[1], t8[5]);                             \
    float t4c = fmaxf(t8[2], t8[6]), t4d = fmaxf(t8[3], t8[7]);                             \
    float vm = fmaxf(fmaxf(t4a, t4b), fmaxf(t4c, t4d));                                     \
    vm = fmaxf(vm, __shfl_xor(vm, 32));                                                     \
    if (!__all(vm <= mrun + 8.f)) {                                                         \
        float nm = fmaxf(mrun, vm);                                                         \
        float al = exp2f(mrun - nm);                                                        \
        _Pragma("unroll")                                                                   \
        for (int i = 0; i < 16; ++i) { ot0[i] *= al; ot1[i] *= al; }                        \
        lrun *= al;                                                                         \
        mrun = nm;                                                                          \
    }                                                                                       \
    _Pragma("unroll")                                                                       \
    for (int i = 0; i < 16; ++i) {                                                          \
        ct0[i] = exp2f(ct0[i] - mrun);                                                      \
        ct1[i] = exp2f(ct1[i] - mrun);                                                      \
    }                                                                                       \
    float s8[8];                                                                            \
    _Pragma("unroll")                                                                       \
    for (int i = 0; i < 8; ++i)                                                             \
        s8[i] = (ct0[i] + ct0[i+8]) + (ct1[i] + ct1[i+8]);                                  \
    float s4a = s8[0]+s8[4], s4b = s8[1]+s8[5], s4c = s8[2]+s8[6], s4d = s8[3]+s8[7];       \
    float ps = (s4a + s4b) + (s4c + s4d);                                                   \
    ps += __shfl_xor(ps, 32);                                                               \
    lrun += ps;                                                                             \
    u32 own0[8], own1[8], oth0[8], oth1[8];                                                 \
    _Pragma("unroll")                                                                       \
    for (int u = 0; u < 8; ++u) {                                                           \
        own0[u] = cvtpk_bf16(ct0[2*u], ct0[2*u+1]);                                         \
        own1[u] = cvtpk_bf16(ct1[2*u], ct1[2*u+1]);                                         \
    }                                                                                       \
    _Pragma("unroll")                                                                       \
    for (int u = 0; u < 8; ++u) {                                                           \
        oth0[u] = __shfl_xor(own0[u], 32);                                                  \
        oth1[u] = __shfl_xor(own1[u], 32);                                                  \
    }                                                                                       \
    __builtin_amdgcn_s_setprio(1);                                                          \
    _Pragma("unroll")                                                                       \
    for (int c = 0; c < 4; ++c) {                                                           \
        const int b0 = 4*(c & 1);                                                           \
        u32 o0, o1, o2, o3, x0, x1, x2, x3;                                                 \
        if ((c >> 1) == 0) {                                                                \
            o0 = own0[b0]; o1 = own0[b0+1]; o2 = own0[b0+2]; o3 = own0[b0+3];               \
            x0 = oth0[b0]; x1 = oth0[b0+1]; x2 = oth0[b0+2]; x3 = oth0[b0+3];               \
        } else {                                                                            \
            o0 = own1[b0]; o1 = own1[b0+1]; o2 = own1[b0+2]; o3 = own1[b0+3];               \
            x0 = oth1[b0]; x1 = oth1[b0+1]; x2 = oth1[b0+2]; x3 = oth1[b0+3];               \
        }                                                                                   \
        u32 w0 = hi ? x2 : o0;                                                              \
        u32 w1 = hi ? x3 : o1;                                                              \
        u32 w2 = hi ? o2 : x0;                                                              \
        u32 w3 = hi ? o3 : x1;                                                              \
        u32x4v pw = { w0, w1, w2, w3 };                                                     \
        bf16x8 pb = __builtin_bit_cast(bf16x8, pw);                                         \
        ot0 = __builtin_amdgcn_mfma_f32_32x32x16_bf16(va0[c], pb, ot0, 0, 0, 0);            \
        ot1 = __builtin_amdgcn_mfma_f32_32x32x16_bf16(va1[c], pb, ot1, 0, 0, 0);            \
    }                                                                                       \
    __builtin_amdgcn_s_setprio(0);                                                          \
} while (0)

__global__ __launch_bounds__(64, 4) void attn_part(
    const bf16* __restrict__ Qf, const bf16* __restrict__ Kf,
    const bf16* __restrict__ Vf, bf16* __restrict__ Opart, float* __restrict__ Mlf)
{
    const int l = threadIdx.x & 63;
    const int l31 = l & 31, hi = l >> 5;
    const int l8 = l*8;

    const int id = (int)blockIdx.x;
    const int bh = id >> 7;                 // consecutive blocks share head -> L2 reuse
    const int rem = id & 127;
    const int qt = 63 - (rem >> 1);         // heavy-first
    const int half = rem & 1;
    const int q0 = qt*32;
    const int qrow = q0 + l31;
    const int widx = (bh*64 + qt)*2 + half;

    const bf16* Qfp = Qf + (size_t)bh*S_*HD_;
    const bf16* Kfp = Kf + (size_t)bh*S_*HD_;
    const bf16* Vfp = Vf + (size_t)bh*S_*HD_;

    const int nkt = q0/64 + 1;              // total tiles (diag tile = nkt-1)
    const int nh0 = nkt - (nkt >> 1);       // ceil half
    const int ts = half ? nh0 : 0;
    const int te = half ? nkt : nh0;

    // Q B-frags (col=q=l31, k=d=dc*16+hi*8+j)
    bf16x8 qb[4];
    #pragma unroll
    for (int dc = 0; dc < 4; ++dc)
        qb[dc] = *(const bf16x8*)(Qfp + (size_t)(((q0 >> 5) << 2) + dc)*512 + l8);

    f32x16 ot0 = {}, ot1 = {};
    float mrun = -1e30f, lrun = 0.f;

    if (ts < te) {
        bf16x8 ka[2][4], kb[2][4];
        #pragma unroll
        for (int kv2 = 0; kv2 < 2; ++kv2)
            #pragma unroll
            for (int dc = 0; dc < 4; ++dc)
                ka[kv2][dc] = *(const bf16x8*)(Kfp + (size_t)((ts*2 + kv2)*4 + dc)*512 + l8);

        int kt = ts;
        while (kt + 1 < te) {
            ATTN_BODY(ka, kb, kt); ++kt;
            ATTN_BODY(kb, ka, kt); ++kt;
        }
        if (kt < te) {
            ATTN_BODY(ka, kb, kt);
        }
    }

    // write partial: unnormalized O (bf16, [d][q] layout) + (m,l) f32
    bf16* Ob = Opart + (size_t)widx*2048;
    #pragma unroll
    for (int rp = 0; rp < 16; ++rp) {
        const int d0 = (rp & 3) + 8*(rp >> 2) + 4*hi;
        Ob[d0*32 + l31]        = (bf16)ot0[rp];
        Ob[(32 + d0)*32 + l31] = (bf16)ot1[rp];
    }
    if (!hi) {
        Mlf[(size_t)widx*64 + l31*2]     = mrun;
        Mlf[(size_t)widx*64 + l31*2 + 1] = lrun;
    }
}

// merge the two key-range partials and write Oat (B,S,D) bf16
__global__ __launch_bounds__(64) void attn_combine(
    const bf16* __restrict__ Opart, const float* __restrict__ Mlf, bf16* __restrict__ Oat)
{
    const int cb = (int)blockIdx.x;         // 0..2047
    const int bh = cb >> 6, qt = cb & 63;
    const int b = bh >> 4, h = bh & 15;
    const int q0 = qt*32;
    const int l = threadIdx.x & 63;
    const int q = l & 31, hi = l >> 5;

    const int w0 = (bh*64 + qt)*2, w1 = w0 + 1;
    const float m0 = Mlf[(size_t)w0*64 + q*2],     l0 = Mlf[(size_t)w0*64 + q*2 + 1];
    const float m1 = Mlf[(size_t)w1*64 + q*2],     l1 = Mlf[(size_t)w1*64 + q*2 + 1];
    const float m = fmaxf(m0, m1);
    const float a0 = exp2f(m0 - m), a1 = exp2f(m1 - m);
    const float inv = 1.f / (l0*a0 + l1*a1);
    const float f0 = a0*inv, f1 = a1*inv;

    const bf16* O0 = Opart + (size_t)w0*2048;
    const bf16* O1 = Opart + (size_t)w1*2048;
    char* rowp = (char*)Oat + (((size_t)(b*S_ + q0 + q)*D_ + h*64 + hi*32)*2);

    #pragma unroll
    for (int i = 0; i < 16; ++i) {
        const int d = hi*32 + 2*i;
        float oA = (float)O0[d*32 + q]*f0       + (float)O1[d*32 + q]*f1;
        float oB = (float)O0[(d+1)*32 + q]*f0   + (float)O1[(d+1)*32 + q]*f1;
        *(u32*)(rowp + 4*i) = cvtpk_bf16(oA, oB);
    }
}

extern "C" void kernel_launch(void* const* d_in, const int* in_sizes, int n_in,
                              void* d_out, int out_size, void* d_ws, size_t ws_size,
                              hipStream_t stream) {
    const float* q  = (const float*)d_in[0];
    const float* k  = (const float*)d_in[1];
    const float* v  = (const float*)d_in[2];
    // d_in[3] = mask (causal, hard-coded in attn kernel)
    const float* wq = (const float*)d_in[4];
    const float* bq = (const float*)d_in[5];
    const float* wk = (const float*)d_in[6];
    const float* bk = (const float*)d_in[7];
    const float* wv = (const float*)d_in[8];
    const float* bv = (const float*)d_in[9];
    const float* wo = (const float*)d_in[10];
    const float* bo = (const float*)d_in[11];
    float* out = (float*)d_out;

    char* p = (char*)d_ws;
    const size_t XSZ = (size_t)M_TOT*D_*sizeof(bf16);   // 8 MiB
    const size_t WSZ = (size_t)D_*D_*sizeof(bf16);      // 2 MiB
    // region A (dead after gemm_qkv; aliased by attn partials):
    bf16* xq  = (bf16*)p;                               // [0,  8M)
    bf16* xk  = (bf16*)(p + XSZ);                       // [8, 16M)
    bf16* xv  = (bf16*)(p + 2*XSZ);                     // [16,24M)
    bf16* wqb = (bf16*)(p + 3*XSZ);                     // [24,26M)
    bf16* wkb = (bf16*)(p + 3*XSZ + WSZ);               // [26,28M)
    bf16* wvb = (bf16*)(p + 3*XSZ + 2*WSZ);             // [28,30M)
    bf16* wob = (bf16*)(p + 3*XSZ + 3*WSZ);             // [30,32M)  LIVE until gemm_out
    bf16* Qf  = (bf16*)(p + 3*XSZ + 4*WSZ);             // [32,40M)
    bf16* Kf  = Qf + M_TOT*D_;                          // [40,48M)
    bf16* Vf  = Kf + M_TOT*D_;                          // [48,56M)
    bf16* Oat = Vf + M_TOT*D_;                          // [56,64M)
    // aliases over dead region A:
    bf16*  Opart = (bf16*)p;                            // [0, 16M)  4096 x 2048 bf16
    float* Mlf   = (float*)(p + 2*XSZ);                 // [16,17M)  4096 x 32 x (m,l)

    cvt_kernel<<<dim3(2048, 7), 256, 0, stream>>>(q, k, v, wq, wk, wv, wo,
                                                  xq, xk, xv, wqb, wkb, wvb, wob);
    gemm_qkv<<<dim3(256, 1, 3), 256, 0, stream>>>(xq, xk, xv, wqb, wkb, wvb,
                                                  bq, bk, bv, Qf, Kf, Vf);
    attn_part<<<4096, 64, 0, stream>>>(Qf, Kf, Vf, Opart, Mlf);
    attn_combine<<<2048, 64, 0, stream>>>(Opart, Mlf, Oat);
    gemm_out<<<dim3(256), 256, 0, stream>>>(Oat, wob, bo, out);
}

// Round 12
// 141.321 us; speedup vs baseline: 2.0768x; 2.0768x over previous
//
#include <hip/hip_runtime.h>
#include <stdint.h>

#define B_ 2
#define S_ 2048
#define D_ 1024
#define H_ 16
#define HD_ 64
#define M_TOT (B_*S_)   // 4096

typedef __bf16 bf16;
typedef bf16 bf16x8 __attribute__((ext_vector_type(8)));
typedef float f32x4 __attribute__((ext_vector_type(4)));
typedef float f32x16 __attribute__((ext_vector_type(16)));
typedef unsigned int u32;
typedef unsigned int u32x4v __attribute__((ext_vector_type(4)));

__device__ __forceinline__ void gload_lds16(const void* g, void* l) {
    __builtin_amdgcn_global_load_lds((const __attribute__((address_space(1))) void*)g,
                                     (__attribute__((address_space(3))) void*)l, 16, 0, 0);
}

__device__ __forceinline__ u32 cvtpk_bf16(float lo, float hi) {
    u32 d;
    asm("v_cvt_pk_bf16_f32 %0, %1, %2" : "=v"(d) : "v"(lo), "v"(hi));
    return d;
}

// ---------------- f32 -> bf16 convert ----------------
__global__ __launch_bounds__(256) void cvt_kernel(
    const float* __restrict__ q, const float* __restrict__ k, const float* __restrict__ v,
    const float* __restrict__ wq, const float* __restrict__ wk,
    const float* __restrict__ wv, const float* __restrict__ wo,
    bf16* __restrict__ xq, bf16* __restrict__ xk, bf16* __restrict__ xv,
    bf16* __restrict__ wqb, bf16* __restrict__ wkb, bf16* __restrict__ wvb, bf16* __restrict__ wob)
{
    const float* src; bf16* dst; int n;
    switch (blockIdx.y) {
        case 0: src=q;  dst=xq;  n=M_TOT*D_; break;
        case 1: src=k;  dst=xk;  n=M_TOT*D_; break;
        case 2: src=v;  dst=xv;  n=M_TOT*D_; break;
        case 3: src=wq; dst=wqb; n=D_*D_;    break;
        case 4: src=wk; dst=wkb; n=D_*D_;    break;
        case 5: src=wv; dst=wvb; n=D_*D_;    break;
        default: src=wo; dst=wob; n=D_*D_;   break;
    }
    int i = (blockIdx.x*blockDim.x + threadIdx.x)*8;
    if (i >= n) return;
    const f32x4* s4 = (const f32x4*)(src + i);
    f32x4 a = s4[0], b = s4[1];
    bf16x8 o;
    #pragma unroll
    for (int j = 0; j < 4; ++j) { o[j] = (bf16)a[j]; o[j+4] = (bf16)b[j]; }
    *(bf16x8*)(dst + i) = o;
}

// ---------------- GEMM mainloop: C[128,128] = A[128,K] * W[128,K]^T ----------------
__device__ __forceinline__ void gemm_mainloop(const bf16* __restrict__ A, const bf16* __restrict__ Wt,
                                              int brow, int bcol, bf16* As, bf16* Bs,
                                              f32x4 (&acc)[4][4])
{
    const int tid = threadIdx.x;
    const int l = tid & 63, w = tid >> 6;
    const int wr = w >> 1, wc = w & 1;
    const int lr = l & 15, lq = l >> 4;

    for (int k0 = 0; k0 < D_; k0 += 32) {
        #pragma unroll
        for (int i = 0; i < 2; ++i) {
            int id = i*256 + tid;
            int row = id >> 2, c8 = (id & 3) << 3;
            gload_lds16(A  + (size_t)(brow + row)*D_ + k0 + c8, As + id*8);
            gload_lds16(Wt + (size_t)(bcol + row)*D_ + k0 + c8, Bs + id*8);
        }
        __syncthreads();
        bf16x8 af[4], bf[4];
        #pragma unroll
        for (int m = 0; m < 4; ++m)
            af[m] = *(const bf16x8*)&As[(wr*64 + m*16 + lr)*32 + lq*8];
        #pragma unroll
        for (int n = 0; n < 4; ++n)
            bf[n] = *(const bf16x8*)&Bs[(wc*64 + n*16 + lr)*32 + lq*8];
        #pragma unroll
        for (int m = 0; m < 4; ++m)
            #pragma unroll
            for (int n = 0; n < 4; ++n)
                acc[m][n] = __builtin_amdgcn_mfma_f32_16x16x32_bf16(af[m], bf[n], acc[m][n], 0, 0, 0);
        __syncthreads();
    }
}

// ---------------- QKV projection GEMM (z: 0=Q,1=K,2=V) ----------------
// Epilogue scatters into MFMA-fragment-major layouts (1KB chunks, lane-ordered):
//  Q/K: chunk=(s>>5)*4+(hd>>4), lane=((hd>>3)&1)<<5 | (s&31), j=hd&7
//  V:   chunk=(s>>6)*8+((s>>4)&3)*2+(hd>>5), lane=((s>>3)&1)<<5 | (hd&31), j=s&7
__global__ __launch_bounds__(256) void gemm_qkv(
    const bf16* __restrict__ xq, const bf16* __restrict__ xk, const bf16* __restrict__ xv,
    const bf16* __restrict__ wqb, const bf16* __restrict__ wkb, const bf16* __restrict__ wvb,
    const float* __restrict__ bq, const float* __restrict__ bk, const float* __restrict__ bv,
    bf16* __restrict__ Qf, bf16* __restrict__ Kf, bf16* __restrict__ Vf)
{
    __shared__ __align__(16) bf16 As[128*32];
    __shared__ __align__(16) bf16 Bs[128*32];
    const int z = blockIdx.z;
    const bf16* A  = (z==0) ? xq  : (z==1) ? xk  : xv;
    const bf16* Wt = (z==0) ? wqb : (z==1) ? wkb : wvb;
    const float* bias = (z==0) ? bq : (z==1) ? bk : bv;

    const int brow = (blockIdx.x & 31)*128;
    const int bcol = (blockIdx.x >> 5)*128;

    f32x4 acc[4][4] = {};
    gemm_mainloop(A, Wt, brow, bcol, As, Bs, acc);

    const int tid = threadIdx.x;
    const int l = tid & 63, w = tid >> 6;
    const int wr = w >> 1, wc = w & 1;
    const int lr = l & 15, lq = l >> 4;

    #pragma unroll
    for (int m = 0; m < 4; ++m)
        #pragma unroll
        for (int n = 0; n < 4; ++n) {
            int col = bcol + wc*64 + n*16 + lr;
            float bv_ = bias[col];
            int h = col >> 6, hd = col & 63;
            #pragma unroll
            for (int r = 0; r < 4; ++r) {
                int row = brow + wr*64 + m*16 + lq*4 + r;
                int b = row >> 11, s = row & 2047;
                float val = acc[m][n][r] + bv_;
                if (z == 0) val *= 0.18033688011112042f;   // 1/sqrt(64) * log2(e) folded into Q
                size_t hbase = ((size_t)b*H_ + h)*S_*HD_;
                if (z < 2) {
                    int chunk = ((s >> 5) << 2) + (hd >> 4);
                    int lane  = (((hd >> 3) & 1) << 5) | (s & 31);
                    bf16* dst = (z==0) ? Qf : Kf;
                    dst[hbase + (size_t)chunk*512 + lane*8 + (hd & 7)] = (bf16)val;
                } else {
                    int chunk = ((s >> 6) << 3) + (((s >> 4) & 3) << 1) + (hd >> 5);
                    int lane  = (((s >> 3) & 1) << 5) | (hd & 31);
                    Vf[hbase + (size_t)chunk*512 + lane*8 + (s & 7)] = (bf16)val;
                }
            }
        }
}

// ---------------- output projection GEMM ----------------
__global__ __launch_bounds__(256) void gemm_out(
    const bf16* __restrict__ Oat, const bf16* __restrict__ wob,
    const float* __restrict__ bo, float* __restrict__ out)
{
    __shared__ __align__(16) bf16 As[128*32];
    __shared__ __align__(16) bf16 Bs[128*32];
    const int brow = (blockIdx.x & 31)*128;
    const int bcol = (blockIdx.x >> 5)*128;

    f32x4 acc[4][4] = {};
    gemm_mainloop(Oat, wob, brow, bcol, As, Bs, acc);

    const int tid = threadIdx.x;
    const int l = tid & 63, w = tid >> 6;
    const int wr = w >> 1, wc = w & 1;
    const int lr = l & 15, lq = l >> 4;

    #pragma unroll
    for (int m = 0; m < 4; ++m)
        #pragma unroll
        for (int n = 0; n < 4; ++n) {
            int col = bcol + wc*64 + n*16 + lr;
            float bv_ = bo[col];
            #pragma unroll
            for (int r = 0; r < 4; ++r) {
                int row = brow + wr*64 + m*16 + lq*4 + r;
                out[(size_t)row*D_ + col] = acc[m][n][r] + bv_;
            }
        }
}

// ---------------- causal flash attention v12: split-K partials, no VGPR cap ----------------
// grid 4096 = 32 bh x 64 qt x 2 halves; 1 wave/block, r7 body.
// launch_bounds(64,2): allocator free (r7 codegen, ~88-128 VGPR, zero scratch);
// residency comes from the GRID (16 blocks/CU = 4 waves/SIMD at VGPR<=128).
// v11's (64,4) cap forced VGPR=64 -> 600MB scratch traffic -> 209us. Reverted.
#define ATTN_BODY(CUR, NXT, KT) do {                                                        \
    const int kc0_ = (KT)*64;                                                               \
    const bool last_ = ((KT) == nkt - 1);                                                   \
    const int ktn_ = ((KT) + 1 < te) ? (KT) + 1 : (KT);                                     \
    _Pragma("unroll")                                                                       \
    for (int kv2 = 0; kv2 < 2; ++kv2)                                                       \
        _Pragma("unroll")                                                                   \
        for (int dc = 0; dc < 4; ++dc)                                                      \
            NXT[kv2][dc] = *(const bf16x8*)(Kfp + (size_t)((ktn_*2 + kv2)*4 + dc)*512 + l8);\
    bf16x8 va0[4], va1[4];                                                                  \
    _Pragma("unroll")                                                                       \
    for (int c = 0; c < 4; ++c) {                                                           \
        va0[c] = *(const bf16x8*)(Vfp + (size_t)((KT)*8 + c*2 + 0)*512 + l8);               \
        va1[c] = *(const bf16x8*)(Vfp + (size_t)((KT)*8 + c*2 + 1)*512 + l8);               \
    }                                                                                       \
    f32x16 ct0 = {}, ct1 = {};                                                              \
    __builtin_amdgcn_s_setprio(1);                                                          \
    _Pragma("unroll")                                                                       \
    for (int dc = 0; dc < 4; ++dc)                                                          \
        ct0 = __builtin_amdgcn_mfma_f32_32x32x16_bf16(CUR[0][dc], qb[dc], ct0, 0, 0, 0);    \
    _Pragma("unroll")                                                                       \
    for (int dc = 0; dc < 4; ++dc)                                                          \
        ct1 = __builtin_amdgcn_mfma_f32_32x32x16_bf16(CUR[1][dc], qb[dc], ct1, 0, 0, 0);    \
    __builtin_amdgcn_s_setprio(0);                                                          \
    if (last_) {                                                                            \
        _Pragma("unroll")                                                                   \
        for (int reg = 0; reg < 16; ++reg) {                                                \
            const int rr = (reg & 3) + 8*(reg >> 2) + 4*hi;                                 \
            if (kc0_ + rr > qrow)      ct0[reg] = -1e30f;                                   \
            if (kc0_ + 32 + rr > qrow) ct1[reg] = -1e30f;                                   \
        }                                                                                   \
    }                                                                                       \
    float t8[8];                                                                            \
    _Pragma("unroll")                                                                       \
    for (int i = 0; i < 8; ++i)                                                             \
        t8[i] = fmaxf(fmaxf(ct0[i], ct0[i+8]), fmaxf(ct1[i], ct1[i+8]));                    \
    float t4a = fmaxf(t8[0], t8[4]), t4b = fmaxf(t8[1], t8[5]);                             \
    float t4c = fmaxf(t8[2], t8[6]), t4d = fmaxf(t8[3], t8[7]);                             \
    float vm = fmaxf(fmaxf(t4a, t4b), fmaxf(t4c, t4d));                                     \
    vm = fmaxf(vm, __shfl_xor(vm, 32));                                                     \
    if (!__all(vm <= mrun + 8.f)) {                                                         \
        float nm = fmaxf(mrun, vm);                                                         \
        float al = exp2f(mrun - nm);                                                        \
        _Pragma("unroll")                                                                   \
        for (int i = 0; i < 16; ++i) { ot0[i] *= al; ot1[i] *= al; }                        \
        lrun *= al;                                                                         \
        mrun = nm;                                                                          \
    }                                                                                       \
    _Pragma("unroll")                                                                       \
    for (int i = 0; i < 16; ++i) {                                                          \
        ct0[i] = exp2f(ct0[i] - mrun);                                                      \
        ct1[i] = exp2f(ct1[i] - mrun);                                                      \
    }                                                                                       \
    float s8[8];                                                                            \
    _Pragma("unroll")                                                                       \
    for (int i = 0; i < 8; ++i)                                                             \
        s8[i] = (ct0[i] + ct0[i+8]) + (ct1[i] + ct1[i+8]);                                  \
    float s4a = s8[0]+s8[4], s4b = s8[1]+s8[5], s4c = s8[2]+s8[6], s4d = s8[3]+s8[7];       \
    float ps = (s4a + s4b) + (s4c + s4d);                                                   \
    ps += __shfl_xor(ps, 32);                                                               \
    lrun += ps;                                                                             \
    u32 own0[8], own1[8], oth0[8], oth1[8];                                                 \
    _Pragma("unroll")                                                                       \
    for (int u = 0; u < 8; ++u) {                                                           \
        own0[u] = cvtpk_bf16(ct0[2*u], ct0[2*u+1]);                                         \
        own1[u] = cvtpk_bf16(ct1[2*u], ct1[2*u+1]);                                         \
    }                                                                                       \
    _Pragma("unroll")                                                                       \
    for (int u = 0; u < 8; ++u) {                                                           \
        oth0[u] = __shfl_xor(own0[u], 32);                                                  \
        oth1[u] = __shfl_xor(own1[u], 32);                                                  \
    }                                                                                       \
    __builtin_amdgcn_s_setprio(1);                                                          \
    _Pragma("unroll")                                                                       \
    for (int c = 0; c < 4; ++c) {                                                           \
        const int b0 = 4*(c & 1);                                                           \
        u32 o0, o1, o2, o3, x0, x1, x2, x3;                                                 \
        if ((c >> 1) == 0) {                                                                \
            o0 = own0[b0]; o1 = own0[b0+1]; o2 = own0[b0+2]; o3 = own0[b0+3];               \
            x0 = oth0[b0]; x1 = oth0[b0+1]; x2 = oth0[b0+2]; x3 = oth0[b0+3];               \
        } else {                                                                            \
            o0 = own1[b0]; o1 = own1[b0+1]; o2 = own1[b0+2]; o3 = own1[b0+3];               \
            x0 = oth1[b0]; x1 = oth1[b0+1]; x2 = oth1[b0+2]; x3 = oth1[b0+3];               \
        }                                                                                   \
        u32 w0 = hi ? x2 : o0;                                                              \
        u32 w1 = hi ? x3 : o1;                                                              \
        u32 w2 = hi ? o2 : x0;                                                              \
        u32 w3 = hi ? o3 : x1;                                                              \
        u32x4v pw = { w0, w1, w2, w3 };                                                     \
        bf16x8 pb = __builtin_bit_cast(bf16x8, pw);                                         \
        ot0 = __builtin_amdgcn_mfma_f32_32x32x16_bf16(va0[c], pb, ot0, 0, 0, 0);            \
        ot1 = __builtin_amdgcn_mfma_f32_32x32x16_bf16(va1[c], pb, ot1, 0, 0, 0);            \
    }                                                                                       \
    __builtin_amdgcn_s_setprio(0);                                                          \
} while (0)

__global__ __launch_bounds__(64, 2) void attn_part(
    const bf16* __restrict__ Qf, const bf16* __restrict__ Kf,
    const bf16* __restrict__ Vf, bf16* __restrict__ Opart, float* __restrict__ Mlf)
{
    const int l = threadIdx.x & 63;
    const int l31 = l & 31, hi = l >> 5;
    const int l8 = l*8;

    const int id = (int)blockIdx.x;
    const int bh = id >> 7;                 // consecutive blocks share head -> L2 reuse
    const int rem = id & 127;
    const int qt = 63 - (rem >> 1);         // heavy-first
    const int half = rem & 1;
    const int q0 = qt*32;
    const int qrow = q0 + l31;
    const int widx = (bh*64 + qt)*2 + half;

    const bf16* Qfp = Qf + (size_t)bh*S_*HD_;
    const bf16* Kfp = Kf + (size_t)bh*S_*HD_;
    const bf16* Vfp = Vf + (size_t)bh*S_*HD_;

    const int nkt = q0/64 + 1;              // total tiles (diag tile = nkt-1)
    const int nh0 = nkt - (nkt >> 1);       // ceil half
    const int ts = half ? nh0 : 0;
    const int te = half ? nkt : nh0;

    // Q B-frags (col=q=l31, k=d=dc*16+hi*8+j)
    bf16x8 qb[4];
    #pragma unroll
    for (int dc = 0; dc < 4; ++dc)
        qb[dc] = *(const bf16x8*)(Qfp + (size_t)(((q0 >> 5) << 2) + dc)*512 + l8);

    f32x16 ot0 = {}, ot1 = {};
    float mrun = -1e30f, lrun = 0.f;

    if (ts < te) {
        bf16x8 ka[2][4], kb[2][4];
        #pragma unroll
        for (int kv2 = 0; kv2 < 2; ++kv2)
            #pragma unroll
            for (int dc = 0; dc < 4; ++dc)
                ka[kv2][dc] = *(const bf16x8*)(Kfp + (size_t)((ts*2 + kv2)*4 + dc)*512 + l8);

        int kt = ts;
        while (kt + 1 < te) {
            ATTN_BODY(ka, kb, kt); ++kt;
            ATTN_BODY(kb, ka, kt); ++kt;
        }
        if (kt < te) {
            ATTN_BODY(ka, kb, kt);
        }
    }

    // write partial: unnormalized O (bf16, [d][q] layout) + (m,l) f32
    bf16* Ob = Opart + (size_t)widx*2048;
    #pragma unroll
    for (int rp = 0; rp < 16; ++rp) {
        const int d0 = (rp & 3) + 8*(rp >> 2) + 4*hi;
        Ob[d0*32 + l31]        = (bf16)ot0[rp];
        Ob[(32 + d0)*32 + l31] = (bf16)ot1[rp];
    }
    if (!hi) {
        Mlf[(size_t)widx*64 + l31*2]     = mrun;
        Mlf[(size_t)widx*64 + l31*2 + 1] = lrun;
    }
}

// merge the two key-range partials and write Oat (B,S,D) bf16
__global__ __launch_bounds__(64) void attn_combine(
    const bf16* __restrict__ Opart, const float* __restrict__ Mlf, bf16* __restrict__ Oat)
{
    const int cb = (int)blockIdx.x;         // 0..2047
    const int bh = cb >> 6, qt = cb & 63;
    const int b = bh >> 4, h = bh & 15;
    const int q0 = qt*32;
    const int l = threadIdx.x & 63;
    const int q = l & 31, hi = l >> 5;

    const int w0 = (bh*64 + qt)*2, w1 = w0 + 1;
    const float m0 = Mlf[(size_t)w0*64 + q*2],     l0 = Mlf[(size_t)w0*64 + q*2 + 1];
    const float m1 = Mlf[(size_t)w1*64 + q*2],     l1 = Mlf[(size_t)w1*64 + q*2 + 1];
    const float m = fmaxf(m0, m1);
    const float a0 = exp2f(m0 - m), a1 = exp2f(m1 - m);
    const float inv = 1.f / (l0*a0 + l1*a1);
    const float f0 = a0*inv, f1 = a1*inv;

    const bf16* O0 = Opart + (size_t)w0*2048;
    const bf16* O1 = Opart + (size_t)w1*2048;
    char* rowp = (char*)Oat + (((size_t)(b*S_ + q0 + q)*D_ + h*64 + hi*32)*2);

    #pragma unroll
    for (int i = 0; i < 16; ++i) {
        const int d = hi*32 + 2*i;
        float oA = (float)O0[d*32 + q]*f0       + (float)O1[d*32 + q]*f1;
        float oB = (float)O0[(d+1)*32 + q]*f0   + (float)O1[(d+1)*32 + q]*f1;
        *(u32*)(rowp + 4*i) = cvtpk_bf16(oA, oB);
    }
}

extern "C" void kernel_launch(void* const* d_in, const int* in_sizes, int n_in,
                              void* d_out, int out_size, void* d_ws, size_t ws_size,
                              hipStream_t stream) {
    const float* q  = (const float*)d_in[0];
    const float* k  = (const float*)d_in[1];
    const float* v  = (const float*)d_in[2];
    // d_in[3] = mask (causal, hard-coded in attn kernel)
    const float* wq = (const float*)d_in[4];
    const float* bq = (const float*)d_in[5];
    const float* wk = (const float*)d_in[6];
    const float* bk = (const float*)d_in[7];
    const float* wv = (const float*)d_in[8];
    const float* bv = (const float*)d_in[9];
    const float* wo = (const float*)d_in[10];
    const float* bo = (const float*)d_in[11];
    float* out = (float*)d_out;

    char* p = (char*)d_ws;
    const size_t XSZ = (size_t)M_TOT*D_*sizeof(bf16);   // 8 MiB
    const size_t WSZ = (size_t)D_*D_*sizeof(bf16);      // 2 MiB
    // region A (dead after gemm_qkv; aliased by attn partials):
    bf16* xq  = (bf16*)p;                               // [0,  8M)
    bf16* xk  = (bf16*)(p + XSZ);                       // [8, 16M)
    bf16* xv  = (bf16*)(p + 2*XSZ);                     // [16,24M)
    bf16* wqb = (bf16*)(p + 3*XSZ);                     // [24,26M)
    bf16* wkb = (bf16*)(p + 3*XSZ + WSZ);               // [26,28M)
    bf16* wvb = (bf16*)(p + 3*XSZ + 2*WSZ);             // [28,30M)
    bf16* wob = (bf16*)(p + 3*XSZ + 3*WSZ);             // [30,32M)  LIVE until gemm_out
    bf16* Qf  = (bf16*)(p + 3*XSZ + 4*WSZ);             // [32,40M)
    bf16* Kf  = Qf + M_TOT*D_;                          // [40,48M)
    bf16* Vf  = Kf + M_TOT*D_;                          // [48,56M)
    bf16* Oat = Vf + M_TOT*D_;                          // [56,64M)
    // aliases over dead region A:
    bf16*  Opart = (bf16*)p;                            // [0, 16M)  4096 x 2048 bf16
    float* Mlf   = (float*)(p + 2*XSZ);                 // [16,17M)  4096 x 32 x (m,l)

    cvt_kernel<<<dim3(2048, 7), 256, 0, stream>>>(q, k, v, wq, wk, wv, wo,
                                                  xq, xk, xv, wqb, wkb, wvb, wob);
    gemm_qkv<<<dim3(256, 1, 3), 256, 0, stream>>>(xq, xk, xv, wqb, wkb, wvb,
                                                  bq, bk, bv, Qf, Kf, Vf);
    attn_part<<<4096, 64, 0, stream>>>(Qf, Kf, Vf, Opart, Mlf);
    attn_combine<<<2048, 64, 0, stream>>>(Opart, Mlf, Oat);
    gemm_out<<<dim3(256), 256, 0, stream>>>(Oat, wob, bo, out);
}

// Round 13
// 130.249 us; speedup vs baseline: 2.2533x; 1.0850x over previous
//
#include <hip/hip_runtime.h>
#include <stdint.h>

#define B_ 2
#define S_ 2048
#define D_ 1024
#define H_ 16
#define HD_ 64
#define M_TOT (B_*S_)   // 4096

typedef __bf16 bf16;
typedef bf16 bf16x8 __attribute__((ext_vector_type(8)));
typedef float f32x4 __attribute__((ext_vector_type(4)));
typedef float f32x16 __attribute__((ext_vector_type(16)));
typedef unsigned int u32;
typedef unsigned int u32x4v __attribute__((ext_vector_type(4)));

__device__ __forceinline__ void gload_lds16(const void* g, void* l) {
    __builtin_amdgcn_global_load_lds((const __attribute__((address_space(1))) void*)g,
                                     (__attribute__((address_space(3))) void*)l, 16, 0, 0);
}

__device__ __forceinline__ u32 cvtpk_bf16(float lo, float hi) {
    u32 d;
    asm("v_cvt_pk_bf16_f32 %0, %1, %2" : "=v"(d) : "v"(lo), "v"(hi));
    return d;
}

// ---------------- f32 -> bf16 convert ----------------
__global__ __launch_bounds__(256) void cvt_kernel(
    const float* __restrict__ q, const float* __restrict__ k, const float* __restrict__ v,
    const float* __restrict__ wq, const float* __restrict__ wk,
    const float* __restrict__ wv, const float* __restrict__ wo,
    bf16* __restrict__ xq, bf16* __restrict__ xk, bf16* __restrict__ xv,
    bf16* __restrict__ wqb, bf16* __restrict__ wkb, bf16* __restrict__ wvb, bf16* __restrict__ wob)
{
    const float* src; bf16* dst; int n;
    switch (blockIdx.y) {
        case 0: src=q;  dst=xq;  n=M_TOT*D_; break;
        case 1: src=k;  dst=xk;  n=M_TOT*D_; break;
        case 2: src=v;  dst=xv;  n=M_TOT*D_; break;
        case 3: src=wq; dst=wqb; n=D_*D_;    break;
        case 4: src=wk; dst=wkb; n=D_*D_;    break;
        case 5: src=wv; dst=wvb; n=D_*D_;    break;
        default: src=wo; dst=wob; n=D_*D_;   break;
    }
    int i = (blockIdx.x*blockDim.x + threadIdx.x)*8;
    if (i >= n) return;
    const f32x4* s4 = (const f32x4*)(src + i);
    f32x4 a = s4[0], b = s4[1];
    bf16x8 o;
    #pragma unroll
    for (int j = 0; j < 4; ++j) { o[j] = (bf16)a[j]; o[j+4] = (bf16)b[j]; }
    *(bf16x8*)(dst + i) = o;
}

// ---------------- GEMM mainloop: C[128,128] = A[128,K] * W[128,K]^T ----------------
__device__ __forceinline__ void gemm_mainloop(const bf16* __restrict__ A, const bf16* __restrict__ Wt,
                                              int brow, int bcol, bf16* As, bf16* Bs,
                                              f32x4 (&acc)[4][4])
{
    const int tid = threadIdx.x;
    const int l = tid & 63, w = tid >> 6;
    const int wr = w >> 1, wc = w & 1;
    const int lr = l & 15, lq = l >> 4;

    for (int k0 = 0; k0 < D_; k0 += 32) {
        #pragma unroll
        for (int i = 0; i < 2; ++i) {
            int id = i*256 + tid;
            int row = id >> 2, c8 = (id & 3) << 3;
            gload_lds16(A  + (size_t)(brow + row)*D_ + k0 + c8, As + id*8);
            gload_lds16(Wt + (size_t)(bcol + row)*D_ + k0 + c8, Bs + id*8);
        }
        __syncthreads();
        bf16x8 af[4], bf[4];
        #pragma unroll
        for (int m = 0; m < 4; ++m)
            af[m] = *(const bf16x8*)&As[(wr*64 + m*16 + lr)*32 + lq*8];
        #pragma unroll
        for (int n = 0; n < 4; ++n)
            bf[n] = *(const bf16x8*)&Bs[(wc*64 + n*16 + lr)*32 + lq*8];
        #pragma unroll
        for (int m = 0; m < 4; ++m)
            #pragma unroll
            for (int n = 0; n < 4; ++n)
                acc[m][n] = __builtin_amdgcn_mfma_f32_16x16x32_bf16(af[m], bf[n], acc[m][n], 0, 0, 0);
        __syncthreads();
    }
}

// ---------------- QKV projection GEMM (z: 0=Q,1=K,2=V) ----------------
// Epilogue scatters into MFMA-fragment-major layouts (1KB chunks, lane-ordered):
//  Q/K: chunk=(s>>5)*4+(hd>>4), lane=((hd>>3)&1)<<5 | (s&31), j=hd&7
//  V:   chunk=(s>>6)*8+((s>>4)&3)*2+(hd>>5), lane=((s>>3)&1)<<5 | (hd&31), j=s&7
__global__ __launch_bounds__(256) void gemm_qkv(
    const bf16* __restrict__ xq, const bf16* __restrict__ xk, const bf16* __restrict__ xv,
    const bf16* __restrict__ wqb, const bf16* __restrict__ wkb, const bf16* __restrict__ wvb,
    const float* __restrict__ bq, const float* __restrict__ bk, const float* __restrict__ bv,
    bf16* __restrict__ Qf, bf16* __restrict__ Kf, bf16* __restrict__ Vf)
{
    __shared__ __align__(16) bf16 As[128*32];
    __shared__ __align__(16) bf16 Bs[128*32];
    const int z = blockIdx.z;
    const bf16* A  = (z==0) ? xq  : (z==1) ? xk  : xv;
    const bf16* Wt = (z==0) ? wqb : (z==1) ? wkb : wvb;
    const float* bias = (z==0) ? bq : (z==1) ? bk : bv;

    const int brow = (blockIdx.x & 31)*128;
    const int bcol = (blockIdx.x >> 5)*128;

    f32x4 acc[4][4] = {};
    gemm_mainloop(A, Wt, brow, bcol, As, Bs, acc);

    const int tid = threadIdx.x;
    const int l = tid & 63, w = tid >> 6;
    const int wr = w >> 1, wc = w & 1;
    const int lr = l & 15, lq = l >> 4;

    #pragma unroll
    for (int m = 0; m < 4; ++m)
        #pragma unroll
        for (int n = 0; n < 4; ++n) {
            int col = bcol + wc*64 + n*16 + lr;
            float bv_ = bias[col];
            int h = col >> 6, hd = col & 63;
            #pragma unroll
            for (int r = 0; r < 4; ++r) {
                int row = brow + wr*64 + m*16 + lq*4 + r;
                int b = row >> 11, s = row & 2047;
                float val = acc[m][n][r] + bv_;
                if (z == 0) val *= 0.18033688011112042f;   // 1/sqrt(64) * log2(e) folded into Q
                size_t hbase = ((size_t)b*H_ + h)*S_*HD_;
                if (z < 2) {
                    int chunk = ((s >> 5) << 2) + (hd >> 4);
                    int lane  = (((hd >> 3) & 1) << 5) | (s & 31);
                    bf16* dst = (z==0) ? Qf : Kf;
                    dst[hbase + (size_t)chunk*512 + lane*8 + (hd & 7)] = (bf16)val;
                } else {
                    int chunk = ((s >> 6) << 3) + (((s >> 4) & 3) << 1) + (hd >> 5);
                    int lane  = (((s >> 3) & 1) << 5) | (hd & 31);
                    Vf[hbase + (size_t)chunk*512 + lane*8 + (s & 7)] = (bf16)val;
                }
            }
        }
}

// ---------------- output projection GEMM ----------------
__global__ __launch_bounds__(256) void gemm_out(
    const bf16* __restrict__ Oat, const bf16* __restrict__ wob,
    const float* __restrict__ bo, float* __restrict__ out)
{
    __shared__ __align__(16) bf16 As[128*32];
    __shared__ __align__(16) bf16 Bs[128*32];
    const int brow = (blockIdx.x & 31)*128;
    const int bcol = (blockIdx.x >> 5)*128;

    f32x4 acc[4][4] = {};
    gemm_mainloop(Oat, wob, brow, bcol, As, Bs, acc);

    const int tid = threadIdx.x;
    const int l = tid & 63, w = tid >> 6;
    const int wr = w >> 1, wc = w & 1;
    const int lr = l & 15, lq = l >> 4;

    #pragma unroll
    for (int m = 0; m < 4; ++m)
        #pragma unroll
        for (int n = 0; n < 4; ++n) {
            int col = bcol + wc*64 + n*16 + lr;
            float bv_ = bo[col];
            #pragma unroll
            for (int r = 0; r < 4; ++r) {
                int row = brow + wr*64 + m*16 + lq*4 + r;
                out[(size_t)row*D_ + col] = acc[m][n][r] + bv_;
            }
        }
}

// ---------------- causal flash attention v13: split-K + XCD-pinned heads ----------------
// grid 4096; xcd=id&7 -> 4 heads/XCD (8MB K/V working set vs 64MB unpinned in v12 ->
// v12's FETCH blew up 12->64MB and in-iteration V loads missed L2). V loads issued
// BEFORE K-next so pre-PV wait is vmcnt(8), not a drain. Body math identical to r7.
#define ATTN_BODY(CUR, NXT, KT) do {                                                        \
    const int kc0_ = (KT)*64;                                                               \
    const bool last_ = ((KT) == nkt - 1);                                                   \
    const int ktn_ = ((KT) + 1 < te) ? (KT) + 1 : (KT);                                     \
    bf16x8 va0[4], va1[4];                                                                  \
    _Pragma("unroll")                                                                       \
    for (int c = 0; c < 4; ++c) {                                                           \
        va0[c] = *(const bf16x8*)(Vfp + (size_t)((KT)*8 + c*2 + 0)*512 + l8);               \
        va1[c] = *(const bf16x8*)(Vfp + (size_t)((KT)*8 + c*2 + 1)*512 + l8);               \
    }                                                                                       \
    _Pragma("unroll")                                                                       \
    for (int kv2 = 0; kv2 < 2; ++kv2)                                                       \
        _Pragma("unroll")                                                                   \
        for (int dc = 0; dc < 4; ++dc)                                                      \
            NXT[kv2][dc] = *(const bf16x8*)(Kfp + (size_t)((ktn_*2 + kv2)*4 + dc)*512 + l8);\
    f32x16 ct0 = {}, ct1 = {};                                                              \
    __builtin_amdgcn_s_setprio(1);                                                          \
    _Pragma("unroll")                                                                       \
    for (int dc = 0; dc < 4; ++dc)                                                          \
        ct0 = __builtin_amdgcn_mfma_f32_32x32x16_bf16(CUR[0][dc], qb[dc], ct0, 0, 0, 0);    \
    _Pragma("unroll")                                                                       \
    for (int dc = 0; dc < 4; ++dc)                                                          \
        ct1 = __builtin_amdgcn_mfma_f32_32x32x16_bf16(CUR[1][dc], qb[dc], ct1, 0, 0, 0);    \
    __builtin_amdgcn_s_setprio(0);                                                          \
    if (last_) {                                                                            \
        _Pragma("unroll")                                                                   \
        for (int reg = 0; reg < 16; ++reg) {                                                \
            const int rr = (reg & 3) + 8*(reg >> 2) + 4*hi;                                 \
            if (kc0_ + rr > qrow)      ct0[reg] = -1e30f;                                   \
            if (kc0_ + 32 + rr > qrow) ct1[reg] = -1e30f;                                   \
        }                                                                                   \
    }                                                                                       \
    float t8[8];                                                                            \
    _Pragma("unroll")                                                                       \
    for (int i = 0; i < 8; ++i)                                                             \
        t8[i] = fmaxf(fmaxf(ct0[i], ct0[i+8]), fmaxf(ct1[i], ct1[i+8]));                    \
    float t4a = fmaxf(t8[0], t8[4]), t4b = fmaxf(t8[1], t8[5]);                             \
    float t4c = fmaxf(t8[2], t8[6]), t4d = fmaxf(t8[3], t8[7]);                             \
    float vm = fmaxf(fmaxf(t4a, t4b), fmaxf(t4c, t4d));                                     \
    vm = fmaxf(vm, __shfl_xor(vm, 32));                                                     \
    if (!__all(vm <= mrun + 8.f)) {                                                         \
        float nm = fmaxf(mrun, vm);                                                         \
        float al = exp2f(mrun - nm);                                                        \
        _Pragma("unroll")                                                                   \
        for (int i = 0; i < 16; ++i) { ot0[i] *= al; ot1[i] *= al; }                        \
        lrun *= al;                                                                         \
        mrun = nm;                                                                          \
    }                                                                                       \
    _Pragma("unroll")                                                                       \
    for (int i = 0; i < 16; ++i) {                                                          \
        ct0[i] = exp2f(ct0[i] - mrun);                                                      \
        ct1[i] = exp2f(ct1[i] - mrun);                                                      \
    }                                                                                       \
    float s8[8];                                                                            \
    _Pragma("unroll")                                                                       \
    for (int i = 0; i < 8; ++i)                                                             \
        s8[i] = (ct0[i] + ct0[i+8]) + (ct1[i] + ct1[i+8]);                                  \
    float s4a = s8[0]+s8[4], s4b = s8[1]+s8[5], s4c = s8[2]+s8[6], s4d = s8[3]+s8[7];       \
    float ps = (s4a + s4b) + (s4c + s4d);                                                   \
    ps += __shfl_xor(ps, 32);                                                               \
    lrun += ps;                                                                             \
    u32 own0[8], own1[8], oth0[8], oth1[8];                                                 \
    _Pragma("unroll")                                                                       \
    for (int u = 0; u < 8; ++u) {                                                           \
        own0[u] = cvtpk_bf16(ct0[2*u], ct0[2*u+1]);                                         \
        own1[u] = cvtpk_bf16(ct1[2*u], ct1[2*u+1]);                                         \
    }                                                                                       \
    _Pragma("unroll")                                                                       \
    for (int u = 0; u < 8; ++u) {                                                           \
        oth0[u] = __shfl_xor(own0[u], 32);                                                  \
        oth1[u] = __shfl_xor(own1[u], 32);                                                  \
    }                                                                                       \
    __builtin_amdgcn_s_setprio(1);                                                          \
    _Pragma("unroll")                                                                       \
    for (int c = 0; c < 4; ++c) {                                                           \
        const int b0 = 4*(c & 1);                                                           \
        u32 o0, o1, o2, o3, x0, x1, x2, x3;                                                 \
        if ((c >> 1) == 0) {                                                                \
            o0 = own0[b0]; o1 = own0[b0+1]; o2 = own0[b0+2]; o3 = own0[b0+3];               \
            x0 = oth0[b0]; x1 = oth0[b0+1]; x2 = oth0[b0+2]; x3 = oth0[b0+3];               \
        } else {                                                                            \
            o0 = own1[b0]; o1 = own1[b0+1]; o2 = own1[b0+2]; o3 = own1[b0+3];               \
            x0 = oth1[b0]; x1 = oth1[b0+1]; x2 = oth1[b0+2]; x3 = oth1[b0+3];               \
        }                                                                                   \
        u32 w0 = hi ? x2 : o0;                                                              \
        u32 w1 = hi ? x3 : o1;                                                              \
        u32 w2 = hi ? o2 : x0;                                                              \
        u32 w3 = hi ? o3 : x1;                                                              \
        u32x4v pw = { w0, w1, w2, w3 };                                                     \
        bf16x8 pb = __builtin_bit_cast(bf16x8, pw);                                         \
        ot0 = __builtin_amdgcn_mfma_f32_32x32x16_bf16(va0[c], pb, ot0, 0, 0, 0);            \
        ot1 = __builtin_amdgcn_mfma_f32_32x32x16_bf16(va1[c], pb, ot1, 0, 0, 0);            \
    }                                                                                       \
    __builtin_amdgcn_s_setprio(0);                                                          \
} while (0)

__global__ __launch_bounds__(64, 2) void attn_part(
    const bf16* __restrict__ Qf, const bf16* __restrict__ Kf,
    const bf16* __restrict__ Vf, bf16* __restrict__ Opart, float* __restrict__ Mlf)
{
    const int l = threadIdx.x & 63;
    const int l31 = l & 31, hi = l >> 5;
    const int l8 = l*8;

    // XCD-pinned decode: xcd = id&7; 4 heads per XCD -> K/V L2-resident
    const int id = (int)blockIdx.x;
    const int xcd = id & 7;
    const int slot = id >> 3;               // 0..511
    const int bh = xcd + 8*(slot >> 7);     // 0..31
    const int rem = slot & 127;
    const int qt = 63 - (rem >> 1);         // heavy-first
    const int half = rem & 1;
    const int q0 = qt*32;
    const int qrow = q0 + l31;
    const int widx = (bh*64 + qt)*2 + half;

    const bf16* Qfp = Qf + (size_t)bh*S_*HD_;
    const bf16* Kfp = Kf + (size_t)bh*S_*HD_;
    const bf16* Vfp = Vf + (size_t)bh*S_*HD_;

    const int nkt = q0/64 + 1;              // total tiles (diag tile = nkt-1)
    const int nh0 = nkt - (nkt >> 1);       // ceil half
    const int ts = half ? nh0 : 0;
    const int te = half ? nkt : nh0;

    // Q B-frags (col=q=l31, k=d=dc*16+hi*8+j)
    bf16x8 qb[4];
    #pragma unroll
    for (int dc = 0; dc < 4; ++dc)
        qb[dc] = *(const bf16x8*)(Qfp + (size_t)(((q0 >> 5) << 2) + dc)*512 + l8);

    f32x16 ot0 = {}, ot1 = {};
    float mrun = -1e30f, lrun = 0.f;

    if (ts < te) {
        bf16x8 ka[2][4], kb[2][4];
        #pragma unroll
        for (int kv2 = 0; kv2 < 2; ++kv2)
            #pragma unroll
            for (int dc = 0; dc < 4; ++dc)
                ka[kv2][dc] = *(const bf16x8*)(Kfp + (size_t)((ts*2 + kv2)*4 + dc)*512 + l8);

        int kt = ts;
        while (kt + 1 < te) {
            ATTN_BODY(ka, kb, kt); ++kt;
            ATTN_BODY(kb, ka, kt); ++kt;
        }
        if (kt < te) {
            ATTN_BODY(ka, kb, kt);
        }
    }

    // write partial: unnormalized O (bf16, [d][q] layout) + (m,l) f32
    bf16* Ob = Opart + (size_t)widx*2048;
    #pragma unroll
    for (int rp = 0; rp < 16; ++rp) {
        const int d0 = (rp & 3) + 8*(rp >> 2) + 4*hi;
        Ob[d0*32 + l31]        = (bf16)ot0[rp];
        Ob[(32 + d0)*32 + l31] = (bf16)ot1[rp];
    }
    if (!hi) {
        Mlf[(size_t)widx*64 + l31*2]     = mrun;
        Mlf[(size_t)widx*64 + l31*2 + 1] = lrun;
    }
}

// merge the two key-range partials and write Oat (B,S,D) bf16
__global__ __launch_bounds__(64) void attn_combine(
    const bf16* __restrict__ Opart, const float* __restrict__ Mlf, bf16* __restrict__ Oat)
{
    const int cb = (int)blockIdx.x;         // 0..2047
    const int bh = cb >> 6, qt = cb & 63;
    const int b = bh >> 4, h = bh & 15;
    const int q0 = qt*32;
    const int l = threadIdx.x & 63;
    const int q = l & 31, hi = l >> 5;

    const int w0 = (bh*64 + qt)*2, w1 = w0 + 1;
    const float m0 = Mlf[(size_t)w0*64 + q*2],     l0 = Mlf[(size_t)w0*64 + q*2 + 1];
    const float m1 = Mlf[(size_t)w1*64 + q*2],     l1 = Mlf[(size_t)w1*64 + q*2 + 1];
    const float m = fmaxf(m0, m1);
    const float a0 = exp2f(m0 - m), a1 = exp2f(m1 - m);
    const float inv = 1.f / (l0*a0 + l1*a1);
    const float f0 = a0*inv, f1 = a1*inv;

    const bf16* O0 = Opart + (size_t)w0*2048;
    const bf16* O1 = Opart + (size_t)w1*2048;
    char* rowp = (char*)Oat + (((size_t)(b*S_ + q0 + q)*D_ + h*64 + hi*32)*2);

    #pragma unroll
    for (int i = 0; i < 16; ++i) {
        const int d = hi*32 + 2*i;
        float oA = (float)O0[d*32 + q]*f0       + (float)O1[d*32 + q]*f1;
        float oB = (float)O0[(d+1)*32 + q]*f0   + (float)O1[(d+1)*32 + q]*f1;
        *(u32*)(rowp + 4*i) = cvtpk_bf16(oA, oB);
    }
}

extern "C" void kernel_launch(void* const* d_in, const int* in_sizes, int n_in,
                              void* d_out, int out_size, void* d_ws, size_t ws_size,
                              hipStream_t stream) {
    const float* q  = (const float*)d_in[0];
    const float* k  = (const float*)d_in[1];
    const float* v  = (const float*)d_in[2];
    // d_in[3] = mask (causal, hard-coded in attn kernel)
    const float* wq = (const float*)d_in[4];
    const float* bq = (const float*)d_in[5];
    const float* wk = (const float*)d_in[6];
    const float* bk = (const float*)d_in[7];
    const float* wv = (const float*)d_in[8];
    const float* bv = (const float*)d_in[9];
    const float* wo = (const float*)d_in[10];
    const float* bo = (const float*)d_in[11];
    float* out = (float*)d_out;

    char* p = (char*)d_ws;
    const size_t XSZ = (size_t)M_TOT*D_*sizeof(bf16);   // 8 MiB
    const size_t WSZ = (size_t)D_*D_*sizeof(bf16);      // 2 MiB
    // region A (dead after gemm_qkv; aliased by attn partials):
    bf16* xq  = (bf16*)p;                               // [0,  8M)
    bf16* xk  = (bf16*)(p + XSZ);                       // [8, 16M)
    bf16* xv  = (bf16*)(p + 2*XSZ);                     // [16,24M)
    bf16* wqb = (bf16*)(p + 3*XSZ);                     // [24,26M)
    bf16* wkb = (bf16*)(p + 3*XSZ + WSZ);               // [26,28M)
    bf16* wvb = (bf16*)(p + 3*XSZ + 2*WSZ);             // [28,30M)
    bf16* wob = (bf16*)(p + 3*XSZ + 3*WSZ);             // [30,32M)  LIVE until gemm_out
    bf16* Qf  = (bf16*)(p + 3*XSZ + 4*WSZ);             // [32,40M)
    bf16* Kf  = Qf + M_TOT*D_;                          // [40,48M)
    bf16* Vf  = Kf + M_TOT*D_;                          // [48,56M)
    bf16* Oat = Vf + M_TOT*D_;                          // [56,64M)
    // aliases over dead region A:
    bf16*  Opart = (bf16*)p;                            // [0, 16M)  4096 x 2048 bf16
    float* Mlf   = (float*)(p + 2*XSZ);                 // [16,17M)  4096 x 32 x (m,l)

    cvt_kernel<<<dim3(2048, 7), 256, 0, stream>>>(q, k, v, wq, wk, wv, wo,
                                                  xq, xk, xv, wqb, wkb, wvb, wob);
    gemm_qkv<<<dim3(256, 1, 3), 256, 0, stream>>>(xq, xk, xv, wqb, wkb, wvb,
                                                  bq, bk, bv, Qf, Kf, Vf);
    attn_part<<<4096, 64, 0, stream>>>(Qf, Kf, Vf, Opart, Mlf);
    attn_combine<<<2048, 64, 0, stream>>>(Opart, Mlf, Oat);
    gemm_out<<<dim3(256), 256, 0, stream>>>(Oat, wob, bo, out);
}